// Round 5
// baseline (28242.468 us; speedup 1.0000x reference)
//
#include <hip/hip_runtime.h>
#include <math.h>

typedef _Float16 h8 __attribute__((ext_vector_type(8)));
typedef float f4 __attribute__((ext_vector_type(4)));
typedef unsigned long long u64;

#define H 1024
#define NBLK 256
#define MAXU 4

// ---- workspace layout (bytes) ----
#define OFF_WRZ0 0ull            // fp16 [2048][1536]
#define OFF_WN0  6291456ull      // fp16 [1024][1536]
#define OFF_WRZ1 9437184ull      // fp16 [2048][2048]
#define OFF_WN1  17825792ull     // fp16 [1024][2048]
#define OFF_H0H  22020096ull     // fp16 [2][64][1024]
#define OFF_H1H  22282240ull     // fp16 [2][64][1024]
#define OFF_RH0  22544384ull     // fp16 [64][1024]
#define OFF_RH1  22675456ull     // fp16 [64][1024]
#define OFF_H0F  22806528ull     // f32 [64][1024]
#define OFF_H1F  23068672ull     // f32 [64][1024]
#define OFF_Z0F  23330816ull     // f32 [64][1024]
#define OFF_Z1F  23592960ull     // f32 [64][1024]
#define OFF_CNT  23855104ull     // u64 [4 ctr][8 shard] stride 16 u64 (128B)
#define OFF_INFO 23859200ull     // u32 [256]
#define OFF_INIT 23860224ull     // u64
#define ZERO_WORDS 460034        // (23860232 - 22020096)/4

// ---------------- LLC-bypass (agent-scope relaxed) helpers — r2/r3-proven ----------------
__device__ __forceinline__ u64 llc_ld64(const void* p) {
  return __hip_atomic_load((const u64*)p, __ATOMIC_RELAXED, __HIP_MEMORY_SCOPE_AGENT);
}
__device__ __forceinline__ unsigned llc_ld32(const void* p) {
  return __hip_atomic_load((const unsigned*)p, __ATOMIC_RELAXED, __HIP_MEMORY_SCOPE_AGENT);
}
__device__ __forceinline__ float llc_ldf(const float* p) {
  return __uint_as_float(llc_ld32(p));
}
__device__ __forceinline__ void llc_st32(void* p, unsigned v) {
  __hip_atomic_store((unsigned*)p, v, __ATOMIC_RELAXED, __HIP_MEMORY_SCOPE_AGENT);
}
union H8U { u64 q[2]; h8 v; };
union H16B { _Float16 h; unsigned short u; };

// ---------------- prep: weights fp32->fp16, zero comm/state region ----------------
__global__ __launch_bounds__(256) void prep_kernel(
    const float* __restrict__ wrz0f, const float* __restrict__ wn0f,
    const float* __restrict__ wrz1f, const float* __restrict__ wn1f,
    _Float16* __restrict__ wrz0, _Float16* __restrict__ wn0,
    _Float16* __restrict__ wrz1, _Float16* __restrict__ wn1,
    unsigned* __restrict__ zbase) {
  size_t i = (size_t)blockIdx.x * blockDim.x + threadIdx.x;
  size_t stride = (size_t)gridDim.x * blockDim.x;
  for (size_t k = i; k < 2048ull * 1536ull; k += stride) wrz0[k] = (_Float16)wrz0f[k];
  for (size_t k = i; k < 1024ull * 1536ull; k += stride) wn0[k]  = (_Float16)wn0f[k];
  for (size_t k = i; k < 2048ull * 2048ull; k += stride) wrz1[k] = (_Float16)wrz1f[k];
  for (size_t k = i; k < 1024ull * 2048ull; k += stride) wn1[k]  = (_Float16)wn1f[k];
  for (size_t k = i; k < (size_t)ZERO_WORDS; k += stride) zbase[k] = 0u;
}

// ---------------- sharded counters: signal own-XCD shard; lane-parallel 8-shard poll ----------------
__device__ __forceinline__ void wait_cnt(u64* base, int c, u64 mult, u64 v) {
  const u64* p = base + (size_t)((c << 3) + (threadIdx.x & 7)) * 16;
  u64 tgt = mult * v;   // mult = this lane's shard signal-count (lanes 8..63 mirror shards 0..7)
  int g = 0;
  while (!__all(llc_ld64(p) >= tgt)) {
    if (++g > (1 << 20)) break;       // fail loud (absmax), never hang
    __builtin_amdgcn_s_sleep(1);
  }
}
// __syncthreads drains all waves' vmcnt -> every LLC store of this block is
// globally visible before thread 0 bumps the counter (r2/r3-proven release).
__device__ __forceinline__ void signal_cnt(u64* base, int c, int xcd) {
  __syncthreads();
  if (threadIdx.x == 0)
    __hip_atomic_fetch_add(base + (size_t)((c << 3) + xcd) * 16, 1ull,
                           __ATOMIC_RELAXED, __HIP_MEMORY_SCOPE_AGENT);
}

// ---------------- GEMM pieces (MFMA 16x16x32 f16, M=16 batch rows, full K per wave) ----------------
__device__ __forceinline__ f4 gemm_x(f4 acc, const float* __restrict__ xrow,
                                     const _Float16* __restrict__ wrow, int kg8) {
#pragma unroll
  for (int kw = 0; kw < 16; ++kw) {
    int k = kw * 32 + kg8;
    float4 f0 = *(const float4*)(xrow + k);
    float4 f1 = *(const float4*)(xrow + k + 4);
    h8 a;
    a[0] = (_Float16)f0.x; a[1] = (_Float16)f0.y; a[2] = (_Float16)f0.z; a[3] = (_Float16)f0.w;
    a[4] = (_Float16)f1.x; a[5] = (_Float16)f1.y; a[6] = (_Float16)f1.z; a[7] = (_Float16)f1.w;
    acc = __builtin_amdgcn_mfma_f32_16x16x32_f16(a, *(const h8*)(wrow + k), acc, 0, 0, 0);
  }
  return acc;
}
// A (fp16, LLC-bypass 8B loads) x W (fp16, normal L2-resident loads); K=1024
__device__ __forceinline__ f4 gemm_h(f4 acc, const _Float16* __restrict__ arow,
                                     const _Float16* __restrict__ wrow, int kg8) {
#pragma unroll
  for (int kw = 0; kw < 32; ++kw) {
    int k = kw * 32 + kg8;
    H8U a; a.q[0] = llc_ld64(arow + k); a.q[1] = llc_ld64(arow + k + 4);
    acc = __builtin_amdgcn_mfma_f32_16x16x32_f16(a.v, *(const h8*)(wrow + k), acc, 0, 0, 0);
  }
  return acc;
}

// prefetch 4 f32 gate inputs for this lane's (rows, col)
__device__ __forceinline__ void pref4(float* dst, const float* src, int cb, int mg) {
  int lane = threadIdx.x & 63;
  int col = cb + (lane & 15);
  int r0 = mg * 16 + ((lane >> 4) << 2);
#pragma unroll
  for (int j = 0; j < 4; ++j) dst[j] = llc_ldf(src + (size_t)(r0 + j) * H + col);
}

// rz apply: sigmoid; r-tiles -> rh (fp16 pair-packed), z-tiles -> zf (f32)
__device__ __forceinline__ void apply_rz_unit(f4 a, int cb, int mg,
    const float* __restrict__ bias, const float* __restrict__ hf, const float* hp,
    _Float16* __restrict__ rh, float* __restrict__ zf) {
  int lane = threadIdx.x & 63;
  int col = cb + (lane & 15);
  int r0 = mg * 16 + ((lane >> 4) << 2);
#pragma unroll
  for (int j = 0; j < 4; ++j) {
    float s = 1.f / (1.f + expf(-(a[j] + bias[col])));
    int row = r0 + j;
    if (cb < 1024) {
      float h = hp ? hp[j] : llc_ldf(hf + (size_t)row * H + col);
      H16B c; c.h = (_Float16)(s * h);
      unsigned pr = (unsigned)__shfl_xor((int)(unsigned)c.u, 1);
      if (!(lane & 1)) llc_st32(rh + (size_t)row * H + col, (unsigned)c.u | (pr << 16));
    } else {
      llc_st32(zf + (size_t)row * H + (col - 1024), __float_as_uint(s));
    }
  }
}

// n apply: tanh + h update -> hf (f32) and hh (fp16 pair-packed)
__device__ __forceinline__ void apply_n_unit(f4 a, int cb, int mg,
    const float* __restrict__ bias, const float* __restrict__ zf,
    const float* __restrict__ hf, const float* pz, const float* ph,
    float* __restrict__ hfout, _Float16* __restrict__ hh) {
  int lane = threadIdx.x & 63;
  int col = cb + (lane & 15);
  int r0 = mg * 16 + ((lane >> 4) << 2);
#pragma unroll
  for (int j = 0; j < 4; ++j) {
    int row = r0 + j;
    float z = pz ? pz[j] : llc_ldf(zf + (size_t)row * H + col);
    float h = ph ? ph[j] : llc_ldf(hf + (size_t)row * H + col);
    float nn = tanhf(a[j] + bias[col]);
    float o = (1.f - z) * nn + z * h;
    llc_st32(hfout + (size_t)row * H + col, __float_as_uint(o));
    H16B c; c.h = (_Float16)o;
    unsigned pr = (unsigned)__shfl_xor((int)(unsigned)c.u, 1);
    if (!(lane & 1)) llc_st32(hh + (size_t)row * H + col, (unsigned)c.u | (pr << 16));
  }
}

struct Unit { int mg; int cb; };
__device__ __forceinline__ Unit dec_rz(int u, int sh0, int X) {
  Unit r; int shi = u >> 6, rem = u & 63;
  r.mg = rem & 3; r.cb = (sh0 + shi * X) * 256 + (rem >> 2) * 16; return r;
}
__device__ __forceinline__ Unit dec_n(int u, int sh0, int X) {
  Unit r; int shi = u >> 5, rem = u & 31;
  r.mg = rem & 3; r.cb = (sh0 + shi * X) * 128 + (rem >> 2) * 16; return r;
}

// ---------------- persistent GRU: whole batch (M=64), XCD-share weights, layer-pipelined ----------------
__global__ __launch_bounds__(256, 1) void gru_main(const float* __restrict__ x,
    const _Float16* __restrict__ wrz0, const _Float16* __restrict__ wn0,
    const _Float16* __restrict__ wrz1, const _Float16* __restrict__ wn1,
    const float* __restrict__ brz0, const float* __restrict__ bn0,
    const float* __restrict__ brz1, const float* __restrict__ bn1,
    _Float16* __restrict__ h0h, _Float16* __restrict__ h1h,
    _Float16* __restrict__ rh0, _Float16* __restrict__ rh1,
    float* __restrict__ h0f, float* __restrict__ h1f,
    float* __restrict__ z0f, float* __restrict__ z1f,
    u64* __restrict__ cnt, unsigned* __restrict__ info, u64* __restrict__ init) {
  __shared__ unsigned char sx[NBLK];
  const int bid = blockIdx.x, tid = threadIdx.x;
  const int lane = tid & 63, wv = tid >> 6;
  const int rsub = lane & 15, kg8 = (lane >> 4) << 3;

  // ---- discovery (agent-scope, r3-proven): publish XCC, read full table ----
  unsigned xcc;
  asm volatile("s_getreg_b32 %0, hwreg(HW_REG_XCC_ID)" : "=s"(xcc));
  xcc &= 7u;
  if (tid == 0) {
    llc_st32(&info[bid], 0x100u | xcc);
    asm volatile("s_waitcnt vmcnt(0)" ::: "memory");
    __hip_atomic_fetch_add(init, 1ull, __ATOMIC_RELAXED, __HIP_MEMORY_SCOPE_AGENT);
    int g = 0;
    while (__hip_atomic_load(init, __ATOMIC_RELAXED, __HIP_MEMORY_SCOPE_AGENT) < (u64)NBLK) {
      if (++g > (1 << 22)) break;
      __builtin_amdgcn_s_sleep(2);
    }
  }
  __syncthreads();
  sx[tid] = (unsigned char)(llc_ld32(&info[tid]) & 7u);
  __syncthreads();

  int rank = 0, mk = 0, mkL = 0, nebits = 0;
  const int myl = tid & 7;
  for (int b = 0; b < NBLK; ++b) {
    int v = sx[b];
    nebits |= 1 << v;
    if (v == (int)xcc) { if (b < bid) rank++; mk++; }
    if (v == myl) mkL++;
  }
  const int X = __popc(nebits);
  const int sh0 = __popc(nebits & ((1 << xcc) - 1));       // compacted share index
  const int nsh = (7 - sh0) / X + 1;                        // shares this XCD covers
  const u64 multL0 = (u64)((mkL + 1) >> 1);                 // per-lane shard counts
  const u64 multL1 = (u64)((mkL == 1) ? 1 : (mkL >> 1));
  const int role = rank & 1;
  const bool doL0 = (role == 0);
  const bool doL1 = (role == 1) || (mk == 1);               // lone block covers both
  const int qL0 = (rank >> 1) * 4 + wv, SL0 = ((mk + 1) >> 1) * 4;
  const int pL1 = (mk == 1) ? 0 : (rank >> 1);
  const int qL1 = pL1 * 4 + wv, SL1 = ((mk == 1) ? 1 : (mk >> 1)) * 4;
  const int totRZ = nsh * 64, totN = nsh * 32;
  const f4 fz = f4{0.f, 0.f, 0.f, 0.f};

  for (int t = 0; t < 512; ++t) {
    const float* xt = x + (size_t)t * 512;
    if (doL0) {
      f4 aRZ[MAXU], aN[MAXU];
      // x-projections (no dependency) BEFORE the hot wait
#pragma unroll
      for (int i = 0; i < MAXU; ++i) {
        int u = qL0 + i * SL0;
        if (u < totRZ) { Unit d = dec_rz(u, sh0, X);
          aRZ[i] = gemm_x(fz, xt + (size_t)(d.mg * 16 + rsub) * 262144,
                          wrz0 + (size_t)(d.cb + rsub) * 1536, kg8); }
        if (u < totN) { Unit d = dec_n(u, sh0, X);
          aN[i] = gemm_x(fz, xt + (size_t)(d.mg * 16 + rsub) * 262144,
                         wn0 + (size_t)(d.cb + rsub) * 1536, kg8); }
      }
      // ---- P0: rz0(t) ----
      if (t >= 1) wait_cnt(cnt, 1, multL0, (u64)t);
      const _Float16* h0prev = h0h + (size_t)((t + 1) & 1) * 65536;
      float hp[MAXU][4];
#pragma unroll
      for (int i = 0; i < MAXU; ++i) {
        int u = qL0 + i * SL0;
        if (u < totRZ) { Unit d = dec_rz(u, sh0, X); if (d.cb < 1024) pref4(hp[i], h0f, d.cb, d.mg); }
      }
#pragma unroll
      for (int i = 0; i < MAXU; ++i) {
        int u = qL0 + i * SL0;
        if (u < totRZ) { Unit d = dec_rz(u, sh0, X);
          f4 a = gemm_h(aRZ[i], h0prev + (size_t)(d.mg * 16 + rsub) * H,
                        wrz0 + (size_t)(d.cb + rsub) * 1536 + 512, kg8);
          apply_rz_unit(a, d.cb, d.mg, brz0, h0f, (d.cb < 1024) ? hp[i] : nullptr, rh0, z0f); }
      }
      for (int u = qL0 + MAXU * SL0; u < totRZ; u += SL0) {  // overflow (rare placements)
        Unit d = dec_rz(u, sh0, X);
        f4 a = gemm_x(fz, xt + (size_t)(d.mg * 16 + rsub) * 262144,
                      wrz0 + (size_t)(d.cb + rsub) * 1536, kg8);
        a = gemm_h(a, h0prev + (size_t)(d.mg * 16 + rsub) * H,
                   wrz0 + (size_t)(d.cb + rsub) * 1536 + 512, kg8);
        apply_rz_unit(a, d.cb, d.mg, brz0, h0f, nullptr, rh0, z0f);
      }
      signal_cnt(cnt, 0, (int)xcc);
      // ---- P1: n0(t) ----
      wait_cnt(cnt, 0, multL0, (u64)(t + 1));
      const bool ovfN = totN > MAXU * SL0;
      if (ovfN && t >= 2) wait_cnt(cnt, 3, multL1, (u64)(t - 1));  // conservative WAR
      float pz[MAXU][4], ph[MAXU][4];
#pragma unroll
      for (int i = 0; i < MAXU; ++i) {
        int u = qL0 + i * SL0;
        if (u < totN) { Unit d = dec_n(u, sh0, X);
          pref4(pz[i], z0f, d.cb, d.mg); pref4(ph[i], h0f, d.cb, d.mg);
          aN[i] = gemm_h(aN[i], rh0 + (size_t)(d.mg * 16 + rsub) * H,
                         wn0 + (size_t)(d.cb + rsub) * 1536 + 512, kg8); }
      }
      if (!ovfN && t >= 2) wait_cnt(cnt, 3, multL1, (u64)(t - 1));  // h0h parity WAR
      _Float16* h0cur = h0h + (size_t)(t & 1) * 65536;
#pragma unroll
      for (int i = 0; i < MAXU; ++i) {
        int u = qL0 + i * SL0;
        if (u < totN) { Unit d = dec_n(u, sh0, X);
          apply_n_unit(aN[i], d.cb, d.mg, bn0, z0f, h0f, pz[i], ph[i], h0f, h0cur); }
      }
      for (int u = qL0 + MAXU * SL0; u < totN; u += SL0) {
        Unit d = dec_n(u, sh0, X);
        f4 a = gemm_x(fz, xt + (size_t)(d.mg * 16 + rsub) * 262144,
                      wn0 + (size_t)(d.cb + rsub) * 1536, kg8);
        a = gemm_h(a, rh0 + (size_t)(d.mg * 16 + rsub) * H,
                   wn0 + (size_t)(d.cb + rsub) * 1536 + 512, kg8);
        apply_n_unit(a, d.cb, d.mg, bn0, z0f, h0f, nullptr, nullptr, h0f, h0cur);
      }
      signal_cnt(cnt, 1, (int)xcc);
    }
    if (doL1) {
      // ---- P2: rz1(t) ----  (h1-part overlapped ahead of the hot c_n0 wait)
      if (t >= 1) wait_cnt(cnt, 3, multL1, (u64)t);
      f4 aZ[MAXU];
      const _Float16* h1prev = h1h + (size_t)((t + 1) & 1) * 65536;
      float hp1[MAXU][4];
#pragma unroll
      for (int i = 0; i < MAXU; ++i) {
        int u = qL1 + i * SL1;
        if (u < totRZ) { Unit d = dec_rz(u, sh0, X);
          aZ[i] = gemm_h(fz, h1prev + (size_t)(d.mg * 16 + rsub) * H,
                         wrz1 + (size_t)(d.cb + rsub) * 2048 + 1024, kg8);
          if (d.cb < 1024) pref4(hp1[i], h1f, d.cb, d.mg); }
      }
      wait_cnt(cnt, 1, multL0, (u64)(t + 1));                // hot: h0(t) ready
      const _Float16* h0cur = h0h + (size_t)(t & 1) * 65536;
#pragma unroll
      for (int i = 0; i < MAXU; ++i) {
        int u = qL1 + i * SL1;
        if (u < totRZ) { Unit d = dec_rz(u, sh0, X);
          f4 a = gemm_h(aZ[i], h0cur + (size_t)(d.mg * 16 + rsub) * H,
                        wrz1 + (size_t)(d.cb + rsub) * 2048, kg8);
          apply_rz_unit(a, d.cb, d.mg, brz1, h1f, (d.cb < 1024) ? hp1[i] : nullptr, rh1, z1f); }
      }
      for (int u = qL1 + MAXU * SL1; u < totRZ; u += SL1) {
        Unit d = dec_rz(u, sh0, X);
        f4 a = gemm_h(fz, h1prev + (size_t)(d.mg * 16 + rsub) * H,
                      wrz1 + (size_t)(d.cb + rsub) * 2048 + 1024, kg8);
        a = gemm_h(a, h0cur + (size_t)(d.mg * 16 + rsub) * H,
                   wrz1 + (size_t)(d.cb + rsub) * 2048, kg8);
        apply_rz_unit(a, d.cb, d.mg, brz1, h1f, nullptr, rh1, z1f);
      }
      signal_cnt(cnt, 2, (int)xcc);
      // ---- P3: n1(t) ----
      wait_cnt(cnt, 2, multL1, (u64)(t + 1));
      float pz1[MAXU][4], ph1[MAXU][4];
      f4 aN1[MAXU];
#pragma unroll
      for (int i = 0; i < MAXU; ++i) {
        int u = qL1 + i * SL1;
        if (u < totN) { Unit d = dec_n(u, sh0, X);
          pref4(pz1[i], z1f, d.cb, d.mg); pref4(ph1[i], h1f, d.cb, d.mg);
          f4 a = gemm_h(fz, h0cur + (size_t)(d.mg * 16 + rsub) * H,
                        wn1 + (size_t)(d.cb + rsub) * 2048, kg8);
          aN1[i] = gemm_h(a, rh1 + (size_t)(d.mg * 16 + rsub) * H,
                          wn1 + (size_t)(d.cb + rsub) * 2048 + 1024, kg8); }
      }
      _Float16* h1cur = h1h + (size_t)(t & 1) * 65536;
#pragma unroll
      for (int i = 0; i < MAXU; ++i) {
        int u = qL1 + i * SL1;
        if (u < totN) { Unit d = dec_n(u, sh0, X);
          apply_n_unit(aN1[i], d.cb, d.mg, bn1, z1f, h1f, pz1[i], ph1[i], h1f, h1cur); }
      }
      for (int u = qL1 + MAXU * SL1; u < totN; u += SL1) {
        Unit d = dec_n(u, sh0, X);
        f4 a = gemm_h(fz, h0cur + (size_t)(d.mg * 16 + rsub) * H,
                      wn1 + (size_t)(d.cb + rsub) * 2048, kg8);
        a = gemm_h(a, rh1 + (size_t)(d.mg * 16 + rsub) * H,
                   wn1 + (size_t)(d.cb + rsub) * 2048 + 1024, kg8);
        apply_n_unit(a, d.cb, d.mg, bn1, z1f, h1f, nullptr, nullptr, h1f, h1cur);
      }
      signal_cnt(cnt, 3, (int)xcc);
    }
  }
}

// ---------------- final fc: out[64,512] = h1 @ Wfc^T + bfc ----------------
__global__ __launch_bounds__(256) void fc_kernel(const float* __restrict__ h1f,
                                                 const float* __restrict__ wfc,
                                                 const float* __restrict__ bfc,
                                                 float* __restrict__ out) {
  const int bid = blockIdx.x;  // 64 blocks x 8 cols
#pragma unroll
  for (int rep = 0; rep < 2; ++rep) {
    int local = threadIdx.x + rep * 256;
    int b = local >> 3;
    int o = bid * 8 + (local & 7);
    const float4* hp = (const float4*)(h1f + (size_t)b * 1024);
    const float4* wp = (const float4*)(wfc + (size_t)o * 1024);
    float s = 0.f;
#pragma unroll 4
    for (int i2 = 0; i2 < 256; ++i2) {
      float4 hv = hp[i2], wv = wp[i2];
      s += hv.x * wv.x + hv.y * wv.y + hv.z * wv.z + hv.w * wv.w;
    }
    out[(size_t)b * 512 + o] = s + bfc[o];
  }
}

extern "C" void kernel_launch(void* const* d_in, const int* in_sizes, int n_in,
                              void* d_out, int out_size, void* d_ws, size_t ws_size,
                              hipStream_t stream) {
  const float* x    = (const float*)d_in[0];
  const float* Wrz0 = (const float*)d_in[1];
  const float* brz0 = (const float*)d_in[2];
  const float* Wn0  = (const float*)d_in[3];
  const float* bn0  = (const float*)d_in[4];
  const float* Wrz1 = (const float*)d_in[5];
  const float* brz1 = (const float*)d_in[6];
  const float* Wn1  = (const float*)d_in[7];
  const float* bn1  = (const float*)d_in[8];
  const float* Wfc  = (const float*)d_in[9];
  const float* bfc  = (const float*)d_in[10];
  float* out = (float*)d_out;
  char* ws = (char*)d_ws;

  _Float16* wrz0h = (_Float16*)(ws + OFF_WRZ0);
  _Float16* wn0h  = (_Float16*)(ws + OFF_WN0);
  _Float16* wrz1h = (_Float16*)(ws + OFF_WRZ1);
  _Float16* wn1h  = (_Float16*)(ws + OFF_WN1);
  _Float16* h0h   = (_Float16*)(ws + OFF_H0H);
  _Float16* h1h   = (_Float16*)(ws + OFF_H1H);
  _Float16* rh0   = (_Float16*)(ws + OFF_RH0);
  _Float16* rh1   = (_Float16*)(ws + OFF_RH1);
  float* h0f = (float*)(ws + OFF_H0F);
  float* h1f = (float*)(ws + OFF_H1F);
  float* z0f = (float*)(ws + OFF_Z0F);
  float* z1f = (float*)(ws + OFF_Z1F);
  u64* cnt = (u64*)(ws + OFF_CNT);
  unsigned* info = (unsigned*)(ws + OFF_INFO);
  u64* init = (u64*)(ws + OFF_INIT);

  prep_kernel<<<2048, 256, 0, stream>>>(Wrz0, Wn0, Wrz1, Wn1,
                                        wrz0h, wn0h, wrz1h, wn1h,
                                        (unsigned*)(ws + OFF_H0H));
  gru_main<<<NBLK, 256, 0, stream>>>(x, wrz0h, wn0h, wrz1h, wn1h,
                                     brz0, bn0, brz1, bn1,
                                     h0h, h1h, rh0, rh1,
                                     h0f, h1f, z0f, z1f,
                                     cnt, info, init);
  fc_kernel<<<64, 256, 0, stream>>>(h1f, Wfc, bfc, out);
}